// Round 1
// baseline (1640.851 us; speedup 1.0000x reference)
//
#include <hip/hip_runtime.h>
#include <cstdint>
#include <type_traits>

namespace {

constexpr int ROWS = 256;          // B*C
constexpr int ROW_N = 65536;       // H*W
constexpr int ST = 1024;           // sort threads per block (16 waves)
constexpr int CHUNKS = ROW_N / ST; // 64
constexpr size_t NTOT = (size_t)ROWS * ROW_N; // 16,777,216

// cos constants (double-precision values of cos(k*pi/5))
constexpr float COS_02PI = 0.80901699437494745f;  // cos(0.2*pi)
constexpr float COS_04PI = 0.30901699437494745f;  // cos(0.4*pi)

struct SortSmem {
    uint32_t hist4[4][256];
    __align__(16) uint32_t whist[16 * 256];
    uint32_t sbase[256];
    uint32_t scanbuf[256];
};

__device__ __forceinline__ uint32_t fkey(float x) {
    // bits of |x|: monotone vs float compare for non-negative finite floats
    return __float_as_uint(fabsf(x));
}

__device__ __forceinline__ uint64_t peer_mask8(uint32_t d) {
    uint64_t m = ~0ull;
#pragma unroll
    for (int b = 0; b < 8; ++b) {
        uint64_t bal = __ballot((d >> b) & 1u);
        m &= (((d >> b) & 1u) != 0u) ? bal : ~bal;
    }
    return m;
}

// Stable LSD radix sort of one row (65536 elems), 4 x 8-bit passes.
// IS_SRC: elements are u64 (key<<16 | idx); else u32 keys only.
template <bool IS_SRC>
__device__ void sort_row(SortSmem& sm, const float* __restrict__ raw,
                         void* bufA, void* bufB, int row)
{
    using ELEM = std::conditional_t<IS_SRC, uint64_t, uint32_t>;
    const int tid = threadIdx.x;
    const int lane = tid & 63;
    const int wave = tid >> 6;
    const uint64_t lane_lt = (1ull << lane) - 1ull;

    const float* rawRow = raw + (size_t)row * ROW_N;
    ELEM* A = (ELEM*)bufA + (size_t)row * ROW_N;
    ELEM* B = (ELEM*)bufB + (size_t)row * ROW_N;

    for (int i = tid; i < 4 * 256; i += ST) ((uint32_t*)sm.hist4)[i] = 0u;
    __syncthreads();

    // Pre-pass: one read of the row builds all 4 digit histograms.
    // Per-wave peer-mask aggregation -> one LDS atomic per (wave,digit).
    for (int c = 0; c < CHUNKS; ++c) {
        uint32_t k = fkey(rawRow[c * ST + tid]);
#pragma unroll
        for (int p = 0; p < 4; ++p) {
            uint32_t d = (k >> (8 * p)) & 255u;
            uint64_t m = peer_mask8(d);
            if ((m & lane_lt) == 0ull)
                atomicAdd(&sm.hist4[p][d], (uint32_t)__popcll(m));
        }
    }
    __syncthreads();

    for (int p = 0; p < 4; ++p) {
        // exclusive scan hist4[p] -> sbase (Hillis-Steele over 256)
        if (tid < 256) sm.scanbuf[tid] = sm.hist4[p][tid];
        __syncthreads();
        for (int s = 1; s < 256; s <<= 1) {
            uint32_t add = 0u;
            if (tid < 256 && tid >= s) add = sm.scanbuf[tid - s];
            __syncthreads();
            if (tid < 256) sm.scanbuf[tid] += add;
            __syncthreads();
        }
        if (tid < 256) sm.sbase[tid] = sm.scanbuf[tid] - sm.hist4[p][tid];
        __syncthreads();

        const ELEM* in = (p & 1) ? A : B;   // p1:A->B  p2:B->A  p3:A->B
        ELEM* out = (p & 1) ? B : A;        // p0: raw->A

        auto load_elem = [&](int c) -> ELEM {
            const int gi = c * ST + tid;
            if (p == 0) {
                uint32_t k = fkey(rawRow[gi]);
                if constexpr (IS_SRC)
                    return (((uint64_t)k) << 16) | (uint32_t)gi;
                else
                    return (ELEM)k;
            }
            return in[gi];
        };

        ELEM v = load_elem(0);
        for (int c = 0; c < CHUNKS; ++c) {
            ELEM vn = (ELEM)0;
            if (c + 1 < CHUNKS) vn = load_elem(c + 1);  // 1-deep prefetch
            ((uint4*)sm.whist)[tid] = make_uint4(0u, 0u, 0u, 0u);
            __syncthreads();                                   // b1
            uint32_t k;
            if constexpr (IS_SRC) k = (uint32_t)(v >> 16);
            else k = (uint32_t)v;
            const uint32_t d = (k >> (8 * p)) & 255u;
            const uint64_t m = peer_mask8(d);
            const uint32_t rw = (uint32_t)__popcll(m & lane_lt);
            if (rw == 0u) sm.whist[wave * 256 + d] = (uint32_t)__popcll(m);
            __syncthreads();                                   // b2
            uint32_t off = sm.sbase[d] + rw;
            for (int w = 0; w < wave; ++w) off += sm.whist[w * 256 + d];
            out[off] = v;                                      // stable scatter
            uint32_t tot = 0u;
            if (tid < 256) {
#pragma unroll
                for (int w = 0; w < 16; ++w) tot += sm.whist[w * 256 + tid];
            }
            __syncthreads();                                   // b3
            if (tid < 256) sm.sbase[tid] += tot;
            v = vn;
        }
        __syncthreads(); // seal this pass's global writes before next pass reads
    }
}

__device__ __forceinline__ float detail_one(float c, float s) {
    const float f = (c < 0.f) ? ((s < 0.f) ? -1.f : COS_04PI)
                              : ((s < 0.f) ? -COS_04PI : 1.f);
    return (0.4f * fabsf(c) + 0.6f * fabsf(s)) * f;
}

} // namespace

__global__ __launch_bounds__(ST)
void sort_merged(const float* __restrict__ ca, const float* __restrict__ sa,
                 void* srcA, void* srcB, void* tgtA, void* tgtB)
{
    __shared__ SortSmem sm;
    if (blockIdx.x < ROWS) sort_row<true>(sm, ca, srcA, srcB, blockIdx.x);
    else                   sort_row<false>(sm, sa, tgtA, tgtB, blockIdx.x - ROWS);
}

__global__ __launch_bounds__(ST)
void sort_src_k(const float* __restrict__ ca, void* srcA, void* srcB)
{
    __shared__ SortSmem sm;
    sort_row<true>(sm, ca, srcA, srcB, blockIdx.x);
}

__global__ __launch_bounds__(ST)
void sort_tgt_k(const float* __restrict__ sa, void* tgtA, void* tgtB)
{
    __shared__ SortSmem sm;
    sort_row<false>(sm, sa, tgtA, tgtB, blockIdx.x);
}

// out0[row, idx[k]] = t_sorted[row, k] * cos(0.8*ph(c) + 0.2*ph(s))
__global__ __launch_bounds__(256)
void approx_finalize(const uint64_t* __restrict__ srcS,
                     const uint32_t* __restrict__ tgtS,
                     const float* __restrict__ ca,
                     const float* __restrict__ sa,
                     float* __restrict__ out0)
{
    const size_t k = (size_t)blockIdx.x * blockDim.x + threadIdx.x;
    const uint64_t v = srcS[k];
    const size_t j = ((k >> 16) << 16) | (uint32_t)(v & 0xFFFFull);
    const float t = __uint_as_float(tgtS[k]);
    const float c = ca[j], s = sa[j];
    const float f = (c < 0.f) ? ((s < 0.f) ? -1.f : -COS_02PI)
                              : ((s < 0.f) ? COS_02PI : 1.f);
    out0[j] = t * f;
}

__global__ __launch_bounds__(256)
void details_kernel(const float4* __restrict__ ch, const float4* __restrict__ sh,
                    const float4* __restrict__ cv, const float4* __restrict__ sv,
                    const float4* __restrict__ cd, const float4* __restrict__ sd,
                    float4* __restrict__ oh, float4* __restrict__ ov,
                    float4* __restrict__ od)
{
    const size_t i = (size_t)blockIdx.x * blockDim.x + threadIdx.x;
    float4 a, b, r;
    a = ch[i]; b = sh[i];
    r.x = detail_one(a.x, b.x); r.y = detail_one(a.y, b.y);
    r.z = detail_one(a.z, b.z); r.w = detail_one(a.w, b.w);
    oh[i] = r;
    a = cv[i]; b = sv[i];
    r.x = detail_one(a.x, b.x); r.y = detail_one(a.y, b.y);
    r.z = detail_one(a.z, b.z); r.w = detail_one(a.w, b.w);
    ov[i] = r;
    a = cd[i]; b = sd[i];
    r.x = detail_one(a.x, b.x); r.y = detail_one(a.y, b.y);
    r.z = detail_one(a.z, b.z); r.w = detail_one(a.w, b.w);
    od[i] = r;
}

extern "C" void kernel_launch(void* const* d_in, const int* in_sizes, int n_in,
                              void* d_out, int out_size, void* d_ws, size_t ws_size,
                              hipStream_t stream)
{
    (void)in_sizes; (void)n_in; (void)out_size;
    const float* ca = (const float*)d_in[0];
    const float* ch = (const float*)d_in[1];
    const float* cv = (const float*)d_in[2];
    const float* cd = (const float*)d_in[3];
    const float* sa = (const float*)d_in[4];
    const float* sh = (const float*)d_in[5];
    const float* sv = (const float*)d_in[6];
    const float* sd = (const float*)d_in[7];

    float* out = (float*)d_out;
    float* out_a = out;
    float* out_h = out + NTOT;
    float* out_v = out + 2 * NTOT;
    float* out_d = out + 3 * NTOT;

    // Scratch layout:
    //  srcA: d_ws[0 .. 134MB)            (u64 ping)
    //  srcB: d_out h+v slots (134MB)     (u64 pong -> final sorted pairs)
    //  tgtA: d_ws (sequential) or d_ws+134MB (merged)
    //  tgtB: d_out d slot (67MB)         (u32 pong -> final sorted keys)
    // finalize reads srcB/tgtB BEFORE details_kernel overwrites those slots.
    uint64_t* srcA = (uint64_t*)d_ws;
    uint64_t* srcB = (uint64_t*)out_h;
    uint32_t* tgtB = (uint32_t*)out_d;

    const size_t SRC_A_BYTES = NTOT * 8;
    const size_t TGT_A_BYTES = NTOT * 4;

    if (ws_size >= SRC_A_BYTES + TGT_A_BYTES) {
        // both sorts concurrently: 512 blocks -> 2 blocks/CU, full occupancy
        uint32_t* tgtA = (uint32_t*)((char*)d_ws + SRC_A_BYTES);
        sort_merged<<<2 * ROWS, ST, 0, stream>>>(ca, sa, srcA, srcB, tgtA, tgtB);
    } else {
        // sequential: tgtA region is reused by srcA afterwards
        uint32_t* tgtA = (uint32_t*)d_ws;
        sort_tgt_k<<<ROWS, ST, 0, stream>>>(sa, tgtA, tgtB);
        sort_src_k<<<ROWS, ST, 0, stream>>>(ca, srcA, srcB);
    }

    approx_finalize<<<(int)(NTOT / 256), 256, 0, stream>>>(srcB, tgtB, ca, sa, out_a);

    details_kernel<<<(int)(NTOT / 4 / 256), 256, 0, stream>>>(
        (const float4*)ch, (const float4*)sh,
        (const float4*)cv, (const float4*)sv,
        (const float4*)cd, (const float4*)sd,
        (float4*)out_h, (float4*)out_v, (float4*)out_d);
}

// Round 2
// 1395.058 us; speedup vs baseline: 1.1762x; 1.1762x over previous
//
#include <hip/hip_runtime.h>
#include <cstdint>
#include <type_traits>

namespace {

constexpr int ROWS = 256;          // B*C
constexpr int ROW_N = 65536;       // H*W
constexpr int ST = 1024;           // sort threads per block (16 waves)
constexpr int CHUNKS = ROW_N / ST; // 64
constexpr size_t NTOT = (size_t)ROWS * ROW_N; // 16,777,216

constexpr float COS_02PI = 0.80901699437494745f;  // cos(0.2*pi)
constexpr float COS_04PI = 0.30901699437494745f;  // cos(0.4*pi)

struct SortSmem {
    __align__(16) uint32_t whist[2][16 * 256]; // 32 KB, double-buffered per-wave digit table
    __align__(16) uint32_t hist[2][256];       // 2 KB, pass-histogram ping-pong
    __align__(16) uint32_t sbase[2][256];      // 2 KB, running digit base ping-pong
};

__device__ __forceinline__ uint32_t fkey(float x) {
    // bits of |x|: monotone vs float compare for non-negative finite floats
    return __float_as_uint(fabsf(x));
}

__device__ __forceinline__ uint64_t peer_mask8(uint32_t d) {
    uint64_t m = ~0ull;
#pragma unroll
    for (int b = 0; b < 8; ++b) {
        uint64_t bal = __ballot((d >> b) & 1u);
        m &= ((d >> b) & 1u) ? bal : ~bal;
    }
    return m;
}

// Stable LSD radix sort of one row (65536 elems), 4 x 8-bit passes (exact).
// IS_SRC: u64 elems = key<<16 | idx | sign(c)<<48 | sign(s)<<49; else u32 keys.
template <bool IS_SRC>
__device__ void sort_row(SortSmem& sm, const float* __restrict__ raw,
                         const float* __restrict__ raw2,
                         void* bufA, void* bufB, int row)
{
    using ELEM = std::conditional_t<IS_SRC, uint64_t, uint32_t>;
    const int tid = threadIdx.x;
    const int lane = tid & 63;
    const int wave = tid >> 6;
    const uint64_t lane_lt = (1ull << lane) - 1ull;

    const float* rawRow = raw + (size_t)row * ROW_N;
    const float* raw2Row = IS_SRC ? (raw2 + (size_t)row * ROW_N) : nullptr;
    ELEM* A = (ELEM*)bufA + (size_t)row * ROW_N;
    ELEM* B = (ELEM*)bufB + (size_t)row * ROW_N;

    // init: zero whist[0] (16KB) + hist[0..1] (2KB)
    {
        uint4 z = make_uint4(0u, 0u, 0u, 0u);
        ((uint4*)sm.whist[0])[tid] = z;
        if (tid < 128) ((uint4*)sm.hist)[tid] = z;
    }
    __syncthreads();

    // prepass: pass-0 histogram (low key byte, ~uniform) via LDS atomics, float4 loads
    {
        const float4* r4 = (const float4*)rawRow;
        for (int c = 0; c < CHUNKS / 4; ++c) {
            float4 f = r4[c * ST + tid];
            atomicAdd(&sm.hist[0][fkey(f.x) & 255u], 1u);
            atomicAdd(&sm.hist[0][fkey(f.y) & 255u], 1u);
            atomicAdd(&sm.hist[0][fkey(f.z) & 255u], 1u);
            atomicAdd(&sm.hist[0][fkey(f.w) & 255u], 1u);
        }
    }
    __syncthreads();

    for (int p = 0; p < 4; ++p) {
        const int cur = p & 1, nxt = cur ^ 1;

        // pass-start: exclusive scan hist[cur] -> sbase[0]; zero hist[cur] for reuse
        if (tid < 64) {
            uint32_t h0 = sm.hist[cur][4 * tid + 0];
            uint32_t h1 = sm.hist[cur][4 * tid + 1];
            uint32_t h2 = sm.hist[cur][4 * tid + 2];
            uint32_t h3 = sm.hist[cur][4 * tid + 3];
            sm.hist[cur][4 * tid + 0] = 0u;
            sm.hist[cur][4 * tid + 1] = 0u;
            sm.hist[cur][4 * tid + 2] = 0u;
            sm.hist[cur][4 * tid + 3] = 0u;
            uint32_t s = h0 + h1 + h2 + h3;
            uint32_t inc = s;
#pragma unroll
            for (int d = 1; d < 64; d <<= 1) {
                uint32_t t = __shfl_up(inc, d, 64);
                if (lane >= d) inc += t;
            }
            uint32_t exc = inc - s;
            sm.sbase[0][4 * tid + 0] = exc;
            sm.sbase[0][4 * tid + 1] = exc + h0;
            sm.sbase[0][4 * tid + 2] = exc + h0 + h1;
            sm.sbase[0][4 * tid + 3] = exc + h0 + h1 + h2;
        }
        __syncthreads();

        const ELEM* inb = (p & 1) ? A : B;  // p1: A->B  p2: B->A  p3: A->B
        ELEM* outb = (p & 1) ? B : A;       // p0: raw->A

        auto load_elem = [&](int c) -> ELEM {
            const int gi = c * ST + tid;
            if (p == 0) {
                float cv = rawRow[gi];
                uint32_t k = fkey(cv);
                if constexpr (IS_SRC) {
                    float sv = raw2Row[gi];
                    uint64_t e = (((uint64_t)k) << 16) | (uint32_t)gi;
                    e |= ((uint64_t)(cv < 0.f ? 1u : 0u)) << 48;
                    e |= ((uint64_t)(sv < 0.f ? 1u : 0u)) << 49;
                    return e;
                } else {
                    return (ELEM)k;
                }
            }
            return inb[gi];
        };

        ELEM v = load_elem(0);
        for (int c = 0; c < CHUNKS; ++c) {
            const int q = c & 1;
            ELEM vn = (ELEM)0;
            if (c + 1 < CHUNKS) vn = load_elem(c + 1);  // prefetch across barriers

            uint32_t k;
            if constexpr (IS_SRC) k = (uint32_t)(v >> 16);
            else k = (uint32_t)v;
            const uint32_t d = (k >> (8 * p)) & 255u;
            const uint64_t m = peer_mask8(d);
            const uint32_t rw = (uint32_t)__popcll(m & lane_lt);
            if (rw == 0u) sm.whist[q][(wave << 8) + d] = (uint32_t)__popcll(m);

            // accumulate next pass's histogram while the element is in registers
            if (p == 2) {
                // top byte is highly skewed -> ballot-aggregated leader atomic
                const uint32_t nd = (k >> 24) & 255u;
                const uint64_t m2 = peer_mask8(nd);
                if ((m2 & lane_lt) == 0ull)
                    atomicAdd(&sm.hist[nxt][nd], (uint32_t)__popcll(m2));
            } else if (p < 2) {
                const uint32_t nd = (k >> (8 * (p + 1))) & 255u;
                atomicAdd(&sm.hist[nxt][nd], 1u);
            }
            __syncthreads();                                   // b_a

            // 256-thread scan: whist[q] -> exclusive prefixes seeded by sbase[q];
            // advance sbase into the other parity; zero the other whist buffer.
            if (tid < 256) {
                uint32_t run = sm.sbase[q][tid];
#pragma unroll
                for (int w = 0; w < 16; ++w) {
                    uint32_t t = sm.whist[q][(w << 8) + tid];
                    sm.whist[q][(w << 8) + tid] = run;
                    run += t;
                }
                sm.sbase[q ^ 1][tid] = run;
#pragma unroll
                for (int w = 0; w < 16; ++w) sm.whist[q ^ 1][(w << 8) + tid] = 0u;
            }
            __syncthreads();                                   // b_b

            outb[sm.whist[q][(wave << 8) + d] + rw] = v;       // stable scatter
            v = vn;
        }
        __syncthreads(); // seal this pass's global writes before next pass reads
    }
}

__device__ __forceinline__ float detail_one(float c, float s) {
    const float f = (c < 0.f) ? ((s < 0.f) ? -1.f : COS_04PI)
                              : ((s < 0.f) ? -COS_04PI : 1.f);
    return (0.4f * fabsf(c) + 0.6f * fabsf(s)) * f;
}

} // namespace

__global__ __launch_bounds__(ST, 8)
void sort_merged(const float* __restrict__ ca, const float* __restrict__ sa,
                 void* srcA, void* srcB, void* tgtA, void* tgtB)
{
    __shared__ SortSmem sm;
    if (blockIdx.x < ROWS) sort_row<true>(sm, ca, sa, srcA, srcB, blockIdx.x);
    else                   sort_row<false>(sm, sa, nullptr, tgtA, tgtB, blockIdx.x - ROWS);
}

__global__ __launch_bounds__(ST, 8)
void sort_src_k(const float* __restrict__ ca, const float* __restrict__ sa,
                void* srcA, void* srcB)
{
    __shared__ SortSmem sm;
    sort_row<true>(sm, ca, sa, srcA, srcB, blockIdx.x);
}

__global__ __launch_bounds__(ST, 8)
void sort_tgt_k(const float* __restrict__ sa, void* tgtA, void* tgtB)
{
    __shared__ SortSmem sm;
    sort_row<false>(sm, sa, nullptr, tgtA, tgtB, blockIdx.x);
}

// out0[row, idx[k]] = t_sorted[row, k] * cos(0.8*ph(c) + 0.2*ph(s)); signs carried in srcS
__global__ __launch_bounds__(256)
void approx_finalize(const uint64_t* __restrict__ srcS,
                     const uint32_t* __restrict__ tgtS,
                     float* __restrict__ out0)
{
    const size_t k = (size_t)blockIdx.x * blockDim.x + threadIdx.x;
    const uint64_t v = srcS[k];
    const size_t j = ((k >> 16) << 16) | (uint32_t)(v & 0xFFFFull);
    const float t = __uint_as_float(tgtS[k]);
    const uint32_t cneg = (uint32_t)(v >> 48) & 1u;
    const uint32_t sneg = (uint32_t)(v >> 49) & 1u;
    const float f = cneg ? (sneg ? -1.f : -COS_02PI)
                         : (sneg ? COS_02PI : 1.f);
    out0[j] = t * f;
}

__global__ __launch_bounds__(256)
void details_kernel(const float4* __restrict__ ch, const float4* __restrict__ sh,
                    const float4* __restrict__ cv, const float4* __restrict__ sv,
                    const float4* __restrict__ cd, const float4* __restrict__ sd,
                    float4* __restrict__ oh, float4* __restrict__ ov,
                    float4* __restrict__ od)
{
    const size_t i = (size_t)blockIdx.x * blockDim.x + threadIdx.x;
    float4 a, b, r;
    a = ch[i]; b = sh[i];
    r.x = detail_one(a.x, b.x); r.y = detail_one(a.y, b.y);
    r.z = detail_one(a.z, b.z); r.w = detail_one(a.w, b.w);
    oh[i] = r;
    a = cv[i]; b = sv[i];
    r.x = detail_one(a.x, b.x); r.y = detail_one(a.y, b.y);
    r.z = detail_one(a.z, b.z); r.w = detail_one(a.w, b.w);
    ov[i] = r;
    a = cd[i]; b = sd[i];
    r.x = detail_one(a.x, b.x); r.y = detail_one(a.y, b.y);
    r.z = detail_one(a.z, b.z); r.w = detail_one(a.w, b.w);
    od[i] = r;
}

extern "C" void kernel_launch(void* const* d_in, const int* in_sizes, int n_in,
                              void* d_out, int out_size, void* d_ws, size_t ws_size,
                              hipStream_t stream)
{
    (void)in_sizes; (void)n_in; (void)out_size;
    const float* ca = (const float*)d_in[0];
    const float* ch = (const float*)d_in[1];
    const float* cv = (const float*)d_in[2];
    const float* cd = (const float*)d_in[3];
    const float* sa = (const float*)d_in[4];
    const float* sh = (const float*)d_in[5];
    const float* sv = (const float*)d_in[6];
    const float* sd = (const float*)d_in[7];

    float* out = (float*)d_out;
    float* out_a = out;
    float* out_h = out + NTOT;
    float* out_v = out + 2 * NTOT;
    float* out_d = out + 3 * NTOT;

    // Scratch layout (4 passes end in B):
    //  srcA: d_ws[0 .. 134MB)            (u64 ping)
    //  srcB: d_out h+v slots (134MB)     (u64 pong -> final sorted pairs+signs)
    //  tgtA: d_ws (sequential) or d_ws+134MB (merged)
    //  tgtB: d_out d slot (67MB)         (u32 pong -> final sorted keys)
    // finalize reads srcB/tgtB BEFORE details_kernel overwrites those slots.
    uint64_t* srcA = (uint64_t*)d_ws;
    uint64_t* srcB = (uint64_t*)out_h;
    uint32_t* tgtB = (uint32_t*)out_d;

    const size_t SRC_A_BYTES = NTOT * 8;
    const size_t TGT_A_BYTES = NTOT * 4;

    if (ws_size >= SRC_A_BYTES + TGT_A_BYTES) {
        uint32_t* tgtA = (uint32_t*)((char*)d_ws + SRC_A_BYTES);
        sort_merged<<<2 * ROWS, ST, 0, stream>>>(ca, sa, srcA, srcB, tgtA, tgtB);
    } else {
        uint32_t* tgtA = (uint32_t*)d_ws;
        sort_tgt_k<<<ROWS, ST, 0, stream>>>(sa, tgtA, tgtB);
        sort_src_k<<<ROWS, ST, 0, stream>>>(ca, sa, srcA, srcB);
    }

    approx_finalize<<<(int)(NTOT / 256), 256, 0, stream>>>(srcB, tgtB, out_a);

    details_kernel<<<(int)(NTOT / 4 / 256), 256, 0, stream>>>(
        (const float4*)ch, (const float4*)sh,
        (const float4*)cv, (const float4*)sv,
        (const float4*)cd, (const float4*)sd,
        (float4*)out_h, (float4*)out_v, (float4*)out_d);
}